// Round 1
// 219.028 us; speedup vs baseline: 1.0611x; 1.0611x over previous
//
#include <hip/hip_runtime.h>

// Problem constants (from setup_inputs): B=64, S=256, W=20, E=128
#define B_ 64
#define S_ 256
#define W_ 20
#define E_ 128
#define NWORDS (B_ * S_)                 // 16384 words
#define VEC    4                         // float4 per thread
#define THREADS_PER_WORD (E_ / VEC)      // 32
#define TOTAL_THREADS (NWORDS * THREADS_PER_WORD)  // 524288

// Native clang vector type — __builtin_nontemporal_{load,store} need this,
// not HIP_vector_type<float,4>.
typedef float f32x4 __attribute__((ext_vector_type(4)));

// out[n, e] = max_{h in [0,20)} ( bias + sum_{k=0..4} x[n, h+k-2, e] * w[k] )
// zero-padded outside [0, W). One thread owns one (word, e4) column:
// 20 coalesced float4 loads (batched up front for MLP), fully-unrolled
// conv + running max, 1 nontemporal float4 store.
//
// NOTE on timing: the harness's timed region includes two ~98 µs 640 MiB
// poison fills (seen in rocprof as fillBufferAligned); the kernel itself
// is ~36 µs vs a ~27 µs streaming roofline (176.2 MB at ~6.5 TB/s).
// This revision: input loads are nontemporal (`nt` flag) — the 167.8 MB
// stream is read-once, so retaining it in L2/L3 only causes eviction
// churn against itself.
__global__ __launch_bounds__(256) void conv_max_kernel(
    const float* __restrict__ x,      // (NWORDS, W_, E_)
    const float* __restrict__ wgt,    // 5 taps
    const float* __restrict__ bias,   // 1
    float* __restrict__ out)          // (NWORDS, E_)
{
    int tid = blockIdx.x * blockDim.x + threadIdx.x;
    int e4  = tid & (THREADS_PER_WORD - 1);   // which float4 along E
    int n   = tid >> 5;                       // word index

    const f32x4* xp = reinterpret_cast<const f32x4*>(x)
                    + (size_t)n * (W_ * E_ / VEC) + e4;

    // Wave-uniform scalar loads (compiler emits s_load; L2-resident, tiny)
    const float w0 = wgt[0], w1 = wgt[1], w2 = wgt[2], w3 = wgt[3], w4 = wgt[4];
    const float b  = bias[0];

    // Pull the whole 20-row column into registers (independent loads -> MLP).
    // Nontemporal: streaming read-once data, don't churn L2/L3.
    f32x4 v[W_];
#pragma unroll
    for (int h = 0; h < W_; ++h) {
        v[h] = __builtin_nontemporal_load(xp + h * (E_ / VEC));
    }

    const float wk[5] = {w0, w1, w2, w3, w4};

    f32x4 m;
#pragma unroll
    for (int h = 0; h < W_; ++h) {
        float ax = b, ay = b, az = b, aw = b;
#pragma unroll
        for (int k = 0; k < 5; ++k) {
            const int src = h + k - 2;        // compile-time resolved bounds
            if (src >= 0 && src < W_) {
                ax = fmaf(v[src].x, wk[k], ax);
                ay = fmaf(v[src].y, wk[k], ay);
                az = fmaf(v[src].z, wk[k], az);
                aw = fmaf(v[src].w, wk[k], aw);
            }
        }
        if (h == 0) {
            m.x = ax; m.y = ay; m.z = az; m.w = aw;
        } else {
            m.x = fmaxf(m.x, ax);
            m.y = fmaxf(m.y, ay);
            m.z = fmaxf(m.z, az);
            m.w = fmaxf(m.w, aw);
        }
    }

    // Output is write-once streaming (8.4 MB) — don't evict the warm input.
    f32x4* outp = reinterpret_cast<f32x4*>(out) + tid;
    __builtin_nontemporal_store(m, outp);
}

extern "C" void kernel_launch(void* const* d_in, const int* in_sizes, int n_in,
                              void* d_out, int out_size, void* d_ws, size_t ws_size,
                              hipStream_t stream) {
    const float* x    = (const float*)d_in[0];  // embedded_char (64,256,20,128) fp32
    const float* wgt  = (const float*)d_in[1];  // conv_w (1,1,5,1) fp32 -> 5 floats
    const float* bias = (const float*)d_in[2];  // conv_b (1,) fp32
    float* out = (float*)d_out;                 // (64,256,128) fp32

    const int threads = 256;
    const int blocks  = TOTAL_THREADS / threads;  // 2048
    conv_max_kernel<<<blocks, threads, 0, stream>>>(x, wgt, bias, out);
}